// Round 12
// baseline (51.028 us; speedup 1.0000x reference)
//
#include <hip/hip_runtime.h>

// FractalEmbedding: tokens -> Julia features (16 fp32) -> 16x2048 projection.
// Output 268 MB fp32 => store-bound. Fill: 7.1 TB/s => ~40.5 us equivalent.
//
// R12 = R11 (TB=128, 1 block/CU, prologue once) but 512 thr (8 waves/CU,
// 2/SIMD for latency cover), 4 dims/thread (one 8 KB contiguous row store
// per token), and 4-token unroll => 4 KB outstanding stores per wave per
// iter, 32 KB/CU in flight (vs 16 KB at R11's 4 waves).

constexpr int TOKENS = 4 * 8192;   // 32768
constexpr int EMBED  = 2048;
constexpr int NF     = 16;         // 2 * STEPS
constexpr int STEPS  = 8;
constexpr int TB     = 128;        // tokens per block -> 256 blocks = 1/CU

typedef float f32x2 __attribute__((ext_vector_type(2)));
typedef float f32x4 __attribute__((ext_vector_type(4)));

__global__ __launch_bounds__(512, 2)
void fused_kernel(const int* __restrict__ tok,
                  const float* __restrict__ crt,
                  const float* __restrict__ cit,
                  const float* __restrict__ W,      // [EMBED][NF]
                  const float* __restrict__ scale_p,
                  float* __restrict__ out)          // [TOKENS][EMBED]
{
    const int tid = threadIdx.x;
    const int d0  = tid * 4;                 // 4 consecutive dims per thread
    const float s = scale_p[0];

    // Packed weights, scale folded: wp[p][k] = {W[d0+2p][k], W[d0+2p+1][k]}*s
    // 32 f32x2 = 64 VGPR.
    f32x2 wp[2][NF];
    {
        const f32x4* W4 = reinterpret_cast<const f32x4*>(W + (size_t)d0 * NF);
        #pragma unroll
        for (int p = 0; p < 2; ++p) {
            #pragma unroll
            for (int k = 0; k < 4; ++k) {
                f32x4 a = W4[p * 8 + k];       // row d0+2p
                f32x4 b = W4[p * 8 + 4 + k];   // row d0+2p+1
                wp[p][4 * k + 0] = (f32x2){ a.x * s, b.x * s };
                wp[p][4 * k + 1] = (f32x2){ a.y * s, b.y * s };
                wp[p][4 * k + 2] = (f32x2){ a.z * s, b.z * s };
                wp[p][4 * k + 3] = (f32x2){ a.w * s, b.w * s };
            }
        }
    }

    // Julia features for this block's 128 tokens -> LDS (8 KB), 2 waves.
    __shared__ float feats[TB][NF];
    const int tok0 = blockIdx.x * TB;
    if (tid < TB) {
        const int t = tok[tok0 + tid];
        const float cr = crt[t];
        const float ci = cit[t];
        float zr = 0.0f, zi = 0.0f;
        #pragma unroll
        for (int st = 0; st < STEPS; ++st) {
            const float nzr = zr * zr - zi * zi + cr;
            const float nzi = 2.0f * zr * zi + ci;
            zr = nzr; zi = nzi;
            feats[tid][2 * st]     = zr;
            feats[tid][2 * st + 1] = zi;
        }
    }
    __syncthreads();

    float* __restrict__ obase = out + (size_t)tok0 * EMBED + d0;

    for (int i = 0; i < TB; i += 4) {
        // Four independent token chains (ILP + 4 KB outstanding stores/wave).
        float f[4][NF];
        #pragma unroll
        for (int t4 = 0; t4 < 4; ++t4) {
            const f32x4* fp = reinterpret_cast<const f32x4*>(feats[i + t4]);
            #pragma unroll
            for (int k = 0; k < 4; ++k) {
                f32x4 v = fp[k];
                f[t4][4 * k + 0] = v.x;
                f[t4][4 * k + 1] = v.y;
                f[t4][4 * k + 2] = v.z;
                f[t4][4 * k + 3] = v.w;
            }
        }
        #pragma unroll
        for (int t4 = 0; t4 < 4; ++t4) {
            f32x2 a0 = {0.f, 0.f}, a1 = {0.f, 0.f};
            #pragma unroll
            for (int k = 0; k < NF; ++k) {
                const f32x2 fk = { f[t4][k], f[t4][k] };
                a0 += fk * wp[0][k];   // v_pk_fma_f32
                a1 += fk * wp[1][k];
            }
            *reinterpret_cast<f32x4*>(obase + (size_t)(i + t4) * EMBED) =
                (f32x4){ a0.x, a0.y, a1.x, a1.y };
        }
    }
}

extern "C" void kernel_launch(void* const* d_in, const int* in_sizes, int n_in,
                              void* d_out, int out_size, void* d_ws, size_t ws_size,
                              hipStream_t stream) {
    const int*   tok   = (const int*)d_in[0];
    const float* crt   = (const float*)d_in[1];
    const float* cit   = (const float*)d_in[2];
    const float* W     = (const float*)d_in[3];
    const float* scale = (const float*)d_in[4];
    float*       out   = (float*)d_out;

    fused_kernel<<<TOKENS / TB, 512, 0, stream>>>(tok, crt, cit, W, scale, out);
}

// Round 13
// 49.877 us; speedup vs baseline: 1.0231x; 1.0231x over previous
//
#include <hip/hip_runtime.h>

// FractalEmbedding: tokens -> Julia features (16 fp32) -> 16x2048 projection.
// Output 268 MB fp32 => store-bound. Fill: 7.1 TB/s => ~40.5 us equivalent.
//
// R13 = R11 (best, 50.2 us: TB=128, 1 block/CU, 256 thr, 8 dims/thread as
// two wave-contiguous quads, pk_fma, 2-token unroll) + ONE change:
// XCD-aware chunked block swizzle (bijective: 256 blocks % 8 XCDs == 0),
// so each XCD's L2 drains one contiguous 32 MB write region instead of
// 8 XCDs interleaving at 1 MB granularity.

constexpr int TOKENS = 4 * 8192;   // 32768
constexpr int EMBED  = 2048;
constexpr int NF     = 16;         // 2 * STEPS
constexpr int STEPS  = 8;
constexpr int TB     = 128;        // tokens per block -> 256 blocks = 1/CU
constexpr int NXCD   = 8;
constexpr int NBLK   = TOKENS / TB;  // 256

typedef float f32x2 __attribute__((ext_vector_type(2)));
typedef float f32x4 __attribute__((ext_vector_type(4)));

__global__ __launch_bounds__(256, 2)
void fused_kernel(const int* __restrict__ tok,
                  const float* __restrict__ crt,
                  const float* __restrict__ cit,
                  const float* __restrict__ W,      // [EMBED][NF]
                  const float* __restrict__ scale_p,
                  float* __restrict__ out)          // [TOKENS][EMBED]
{
    // XCD-chunked swizzle: hardware round-robins blockIdx across 8 XCDs;
    // remap so XCD x gets the contiguous chunk [x*32, (x+1)*32) of regions.
    const int bid  = blockIdx.x;
    const int blk  = (bid % NXCD) * (NBLK / NXCD) + (bid / NXCD);

    const int tid  = threadIdx.x;
    const int wv   = tid >> 6;          // wave 0..3
    const int lane = tid & 63;
    const int dA   = wv * 512 + lane * 4;   // quad A: dense 1 KB across wave
    const int dB   = dA + 256;              // quad B: adjacent dense 1 KB
    const float s  = scale_p[0];

    // Packed weights, scale folded: wp[c][p][k] = {W[d+2p][k], W[d+2p+1][k]}*s
    f32x2 wp[2][2][NF];
    #pragma unroll
    for (int c = 0; c < 2; ++c) {
        const int d = (c == 0) ? dA : dB;
        const f32x4* W4 = reinterpret_cast<const f32x4*>(W + (size_t)d * NF);
        #pragma unroll
        for (int p = 0; p < 2; ++p) {
            #pragma unroll
            for (int k = 0; k < 4; ++k) {
                f32x4 a = W4[p * 8 + k];       // row d+2p
                f32x4 b = W4[p * 8 + 4 + k];   // row d+2p+1
                wp[c][p][4 * k + 0] = (f32x2){ a.x * s, b.x * s };
                wp[c][p][4 * k + 1] = (f32x2){ a.y * s, b.y * s };
                wp[c][p][4 * k + 2] = (f32x2){ a.z * s, b.z * s };
                wp[c][p][4 * k + 3] = (f32x2){ a.w * s, b.w * s };
            }
        }
    }

    // Julia features for this block's 128 tokens -> LDS (8 KB), 2 waves.
    __shared__ float feats[TB][NF];
    const int tok0 = blk * TB;
    if (tid < TB) {
        const int t = tok[tok0 + tid];
        const float cr = crt[t];
        const float ci = cit[t];
        float zr = 0.0f, zi = 0.0f;
        #pragma unroll
        for (int st = 0; st < STEPS; ++st) {
            const float nzr = zr * zr - zi * zi + cr;
            const float nzi = 2.0f * zr * zi + ci;
            zr = nzr; zi = nzi;
            feats[tid][2 * st]     = zr;
            feats[tid][2 * st + 1] = zi;
        }
    }
    __syncthreads();

    float* __restrict__ oA = out + (size_t)tok0 * EMBED + dA;
    float* __restrict__ oB = out + (size_t)tok0 * EMBED + dB;

    for (int i = 0; i < TB; i += 2) {
        float fa[NF], fb[NF];
        {
            const f32x4* fpa = reinterpret_cast<const f32x4*>(feats[i]);
            const f32x4* fpb = reinterpret_cast<const f32x4*>(feats[i + 1]);
            #pragma unroll
            for (int k = 0; k < 4; ++k) {
                f32x4 va = fpa[k], vb = fpb[k];
                fa[4 * k + 0] = va.x; fa[4 * k + 1] = va.y;
                fa[4 * k + 2] = va.z; fa[4 * k + 3] = va.w;
                fb[4 * k + 0] = vb.x; fb[4 * k + 1] = vb.y;
                fb[4 * k + 2] = vb.z; fb[4 * k + 3] = vb.w;
            }
        }
        f32x2 aA0 = {0.f,0.f}, aA1 = {0.f,0.f}, aB0 = {0.f,0.f}, aB1 = {0.f,0.f};
        f32x2 bA0 = {0.f,0.f}, bA1 = {0.f,0.f}, bB0 = {0.f,0.f}, bB1 = {0.f,0.f};
        #pragma unroll
        for (int k = 0; k < NF; ++k) {
            const f32x2 fA = { fa[k], fa[k] };
            const f32x2 fB = { fb[k], fb[k] };
            aA0 += fA * wp[0][0][k];   // v_pk_fma_f32
            aA1 += fA * wp[0][1][k];
            aB0 += fA * wp[1][0][k];
            aB1 += fA * wp[1][1][k];
            bA0 += fB * wp[0][0][k];
            bA1 += fB * wp[0][1][k];
            bB0 += fB * wp[1][0][k];
            bB1 += fB * wp[1][1][k];
        }
        const size_t r0 = (size_t)i * EMBED;
        const size_t r1 = (size_t)(i + 1) * EMBED;
        *reinterpret_cast<f32x4*>(oA + r0) = (f32x4){ aA0.x, aA0.y, aA1.x, aA1.y };
        *reinterpret_cast<f32x4*>(oB + r0) = (f32x4){ aB0.x, aB0.y, aB1.x, aB1.y };
        *reinterpret_cast<f32x4*>(oA + r1) = (f32x4){ bA0.x, bA0.y, bA1.x, bA1.y };
        *reinterpret_cast<f32x4*>(oB + r1) = (f32x4){ bB0.x, bB0.y, bB1.x, bB1.y };
    }
}

extern "C" void kernel_launch(void* const* d_in, const int* in_sizes, int n_in,
                              void* d_out, int out_size, void* d_ws, size_t ws_size,
                              hipStream_t stream) {
    const int*   tok   = (const int*)d_in[0];
    const float* crt   = (const float*)d_in[1];
    const float* cit   = (const float*)d_in[2];
    const float* W     = (const float*)d_in[3];
    const float* scale = (const float*)d_in[4];
    float*       out   = (float*)d_out;

    fused_kernel<<<NBLK, 256, 0, stream>>>(tok, crt, cit, W, scale, out);
}